// Round 2
// baseline (556.877 us; speedup 1.0000x reference)
//
#include <hip/hip_runtime.h>

#define T_STEPS 1000
#define B_TOT   2048
#define I_IN    40
#define H_N     16
#define TC      40
#define NCHUNK  25
#define EPB     2
#define BLOCK   256
#define XROW    44                 // padded row stride (floats): 16B-aligned rows, conflict-free 4-addr reads
#define XBUF_E  (TC*XROW)          // 1760 floats per elem
#define CBUF_E  (32*XROW)          // 1408 floats per elem
#define NUNIT   (EPB*TC*I_IN/4)    // 800 float4 staging units per chunk
#define LOGITS_OFF 1
#define CORR_OFF  (1 + 2*B_TOT*T_STEPS)   // 4096001
#define TOTAL_OFF (CORR_OFF + 1)          // 4096002

typedef float v2f __attribute__((ext_vector_type(2)));

__global__ void snn_init(float* out) {
    out[0] = 0.0f;
    out[CORR_OFF] = 0.0f;
    out[TOTAL_OFF] = 1216512.0f;   // 594 flagged steps * 2048 batch
}

// quad_perm 0xB1: swap lanes (2k,2k+1) — pure-VALU branch-pair exchange
__device__ __forceinline__ float dpp_xor1(float v) {
    return __int_as_float(__builtin_amdgcn_update_dpp(0, __float_as_int(v), 0xB1, 0xF, 0xF, true));
}

__global__ __launch_bounds__(BLOCK, 4) void snn_main(
    const float* __restrict__ x, const int* __restrict__ target,
    const float* __restrict__ W1, const float* __restrict__ tau_m,
    const float* __restrict__ tau_n, const float* __restrict__ mask,
    const float* __restrict__ W2, const float* __restrict__ b2,
    float* __restrict__ out)
{
    __shared__ __align__(16) float xbuf[EPB*XBUF_E];     // [e][t(40)][44]
    __shared__ __align__(16) float curbuf[EPB*CBUF_E];   // [e][r(32)][44]
    __shared__ unsigned long long smaskbuf[2][TC];       // per-step 64-lane ballots
    __shared__ float w2s[2*H_N];

    const int tid  = threadIdx.x;
    const int wv   = tid >> 6;
    const int lane = tid & 63;
    const int e    = tid >> 7;            // phase-A elem
    const int r    = (tid >> 2) & 31;     // phase-A dendritic row
    const int tg   = tid & 3;             // phase-A t-group (10 consecutive t)
    const int b0   = blockIdx.x * EPB;

    if (tid < 2*H_N) w2s[tid] = W2[tid];

    // per-thread full-row weights, packed (q0,q1)/(q2,q3) pairs per j for pk_fma
    v2f w01[10], w23[10];
#pragma unroll
    for (int j = 0; j < 10; ++j) {
        const float4 wa = *(const float4*)(W1 + r*I_IN + 4*j);
        const float4 ma = *(const float4*)(mask + r*I_IN + 4*j);
        w01[j] = (v2f){wa.x*ma.x, wa.y*ma.y};
        w23[j] = (v2f){wa.z*ma.z, wa.w*ma.w};
    }

    // phase-B role: one wave per block, rotated across blocks to spread SIMDs
    const int pb   = blockIdx.x & 3;
    const int be   = lane >> 5;           // phase-B elem
    const int brow = lane & 31;           // phase-B row
    const float alpha = 1.0f / (1.0f + __expf(-tau_m[brow >> 1]));
    const float beta  = 1.0f / (1.0f + __expf(-tau_n[brow]));
    const float b2v0  = b2[0];
    const float b2v1  = b2[1];

    // comb roles: the two waves after pb (mod 4); lane<40 handles (ce, t=lane)
    const int ow0 = (pb + 1) & 3, ow1 = (pb + 2) & 3;
    const int ce  = (wv == ow1) ? 1 : 0;
    const bool combwave = (wv == ow0) || (wv == ow1);
    const bool iscomb   = combwave && (lane < TC);

    // staging: unit u -> x[(b0+eu), trow, 4*f4..], contiguous float4, linear->padded LDS
    int goff0, goff1, goff2, goff3 = 0, loff0, loff1, loff2, loff3 = 0;
    {
        int u = tid;             { const int eu = u/400, rem = u%400, trow = rem/10, f4 = rem%10;
            goff0 = ((b0+eu)*T_STEPS + trow)*I_IN + 4*f4; loff0 = eu*XBUF_E + trow*XROW + 4*f4; }
        u = tid + 256;           { const int eu = u/400, rem = u%400, trow = rem/10, f4 = rem%10;
            goff1 = ((b0+eu)*T_STEPS + trow)*I_IN + 4*f4; loff1 = eu*XBUF_E + trow*XROW + 4*f4; }
        u = tid + 512;           { const int eu = u/400, rem = u%400, trow = rem/10, f4 = rem%10;
            goff2 = ((b0+eu)*T_STEPS + trow)*I_IN + 4*f4; loff2 = eu*XBUF_E + trow*XROW + 4*f4; }
        if (tid < 32) { u = tid + 768; const int eu = u/400, rem = u%400, trow = rem/10, f4 = rem%10;
            goff3 = ((b0+eu)*T_STEPS + trow)*I_IN + 4*f4; loff3 = eu*XBUF_E + trow*XROW + 4*f4; }
    }
    float4 pf0 = *(const float4*)(x + goff0);
    float4 pf1 = *(const float4*)(x + goff1);
    float4 pf2 = *(const float4*)(x + goff2);
    float4 pf3 = (tid < 32) ? *(const float4*)(x + goff3) : make_float4(0,0,0,0);

    float d = 0.0f, mem = 0.0f, spk = 0.0f;
    float acc_loss = 0.0f, acc_corr = 0.0f;
    unsigned long long cap = 0;

    for (int c = 0; c < NCHUNK; ++c) {
        // stage chunk c (race-free: phase-A reads of prev chunk fenced by prev B2)
        *(float4*)(xbuf + loff0) = pf0;
        *(float4*)(xbuf + loff1) = pf1;
        *(float4*)(xbuf + loff2) = pf2;
        if (tid < 32) *(float4*)(xbuf + loff3) = pf3;
        __syncthreads();   // B1
        if (c + 1 < NCHUNK) {
            const int tadd = (c + 1) * (TC * I_IN);
            pf0 = *(const float4*)(x + tadd + goff0);
            pf1 = *(const float4*)(x + tadd + goff1);
            pf2 = *(const float4*)(x + tadd + goff2);
            if (tid < 32) pf3 = *(const float4*)(x + tadd + goff3);
        }

        // phase A: 10 full-row dots, all in-lane; bit-exact s_q sequential, (s0+s1)+(s2+s3)
        {
            const float* xb = xbuf + e*XBUF_E;
            float* cb = curbuf + e*CBUF_E + r*XROW;
#pragma unroll
            for (int jj = 0; jj < 10; ++jj) {
                const int trow = tg*10 + jj;
                const float* xp = xb + trow*XROW;
                v2f s01 = {0.0f, 0.0f}, s23 = {0.0f, 0.0f};
#pragma unroll
                for (int j = 0; j < 10; ++j) {
                    const float4 xv = *(const float4*)(xp + 4*j);
                    const v2f xlo = {xv.x, xv.y};
                    const v2f xhi = {xv.z, xv.w};
                    s01 = __builtin_elementwise_fma(w01[j], xlo, s01);
                    s23 = __builtin_elementwise_fma(w23[j], xhi, s23);
                }
                cb[trow] = (s01.x + s01.y) + (s23.x + s23.y);
            }
        }

        // comb for chunk c-1 (ballots fenced by B1; overlaps phase A issue window)
        if (c > 0 && iscomb) {
            const unsigned long long m = smaskbuf[(c-1) & 1][lane];
            const int t = (c-1)*TC + lane;
            float sL0 = b2v0, sL1 = b2v1;
#pragma unroll
            for (int nn = 0; nn < H_N; ++nn) {   // same fma order as ref -> bit-exact logits
                const float f = (float)((unsigned)(m >> (ce*32 + 2*nn)) & 1u);
                sL0 = fmaf(f, w2s[nn], sL0);
                sL1 = fmaf(f, w2s[H_N + nn], sL1);
            }
            const int b = b0 + ce;
            const int oidx = (b*T_STEPS + t)*2;
            out[LOGITS_OFF + oidx]     = sL0;
            out[LOGITS_OFF + oidx + 1] = sL1;
            const bool flag = (t > 10) && (((t - 10) % 15) > 5);
            if (flag) {
                const int tgt = target[b*T_STEPS + t];
                float mx  = fmaxf(sL0, sL1);
                float e0  = __expf(sL0 - mx), e1 = __expf(sL1 - mx);
                float inv = 1.0f / (e0 + e1);
                float p0  = e0*inv, p1 = e1*inv;
                float mm  = fmaxf(p0, p1);
                float lse = mm + __logf(__expf(p0 - mm) + __expf(p1 - mm));
                float qv  = ((tgt == 1) ? p1 : p0) - lse;
                acc_loss -= qv;
                const int pred = (p1 > p0) ? 1 : 0;
                acc_corr += (pred == tgt) ? 1.0f : 0.0f;
            }
        }
        __syncthreads();   // B2: curbuf ready

        // phase B: single wave runs the 40-step recurrence for both elems
        if (wv == pb) {
            const float* cp = curbuf + be*CBUF_E + brow*XROW;
#pragma unroll
            for (int tb = 0; tb < 10; ++tb) {
                const float4 cv = *(const float4*)(cp + 4*tb);
#pragma unroll
                for (int k = 0; k < 4; ++k) {
                    const float cur = (k == 0) ? cv.x : (k == 1) ? cv.y : (k == 2) ? cv.z : cv.w;
                    d = fmaf(beta, d - cur, cur);
                    const float l = d + dpp_xor1(d);       // d[2n]+d[2n+1], lane-pair exact
                    mem = fmaf(alpha, (mem - spk) - l, l);
                    const bool fired = mem > 1.0f;
                    spk = fired ? 1.0f : 0.0f;
                    const unsigned long long bal = __ballot(fired);
                    if (lane == tb*4 + k) cap = bal;
                }
            }
            if (lane < TC) smaskbuf[c & 1][lane] = cap;
        }
    }

    // tail: comb for the last chunk
    __syncthreads();
    if (iscomb) {
        const unsigned long long m = smaskbuf[(NCHUNK-1) & 1][lane];
        const int t = (NCHUNK-1)*TC + lane;
        float sL0 = b2v0, sL1 = b2v1;
#pragma unroll
        for (int nn = 0; nn < H_N; ++nn) {
            const float f = (float)((unsigned)(m >> (ce*32 + 2*nn)) & 1u);
            sL0 = fmaf(f, w2s[nn], sL0);
            sL1 = fmaf(f, w2s[H_N + nn], sL1);
        }
        const int b = b0 + ce;
        const int oidx = (b*T_STEPS + t)*2;
        out[LOGITS_OFF + oidx]     = sL0;
        out[LOGITS_OFF + oidx + 1] = sL1;
        const bool flag = (t > 10) && (((t - 10) % 15) > 5);
        if (flag) {
            const int tgt = target[b*T_STEPS + t];
            float mx  = fmaxf(sL0, sL1);
            float e0  = __expf(sL0 - mx), e1 = __expf(sL1 - mx);
            float inv = 1.0f / (e0 + e1);
            float p0  = e0*inv, p1 = e1*inv;
            float mm  = fmaxf(p0, p1);
            float lse = mm + __logf(__expf(p0 - mm) + __expf(p1 - mm));
            float qv  = ((tgt == 1) ? p1 : p0) - lse;
            acc_loss -= qv;
            const int pred = (p1 > p0) ? 1 : 0;
            acc_corr += (pred == tgt) ? 1.0f : 0.0f;
        }
    }

    if (combwave) {
        acc_loss *= (1.0f / (float)B_TOT);
#pragma unroll
        for (int mk = 1; mk < 64; mk <<= 1) {
            acc_loss += __shfl_xor(acc_loss, mk, 64);
            acc_corr += __shfl_xor(acc_corr, mk, 64);
        }
        if (lane == 0) {
            atomicAdd(out, acc_loss);
            atomicAdd(out + CORR_OFF, acc_corr);
        }
    }
}

extern "C" void kernel_launch(void* const* d_in, const int* in_sizes, int n_in,
                              void* d_out, int out_size, void* d_ws, size_t ws_size,
                              hipStream_t stream) {
    const float* x      = (const float*)d_in[0];
    const int*   target = (const int*)d_in[1];
    const float* W1     = (const float*)d_in[2];
    const float* tau_m  = (const float*)d_in[3];
    const float* tau_n  = (const float*)d_in[4];
    const float* mask   = (const float*)d_in[5];
    const float* W2     = (const float*)d_in[6];
    const float* b2     = (const float*)d_in[7];
    float* out = (float*)d_out;

    snn_init<<<1, 1, 0, stream>>>(out);
    snn_main<<<B_TOT/EPB, BLOCK, 0, stream>>>(x, target, W1, tau_m, tau_n, mask, W2, b2, out);
}

// Round 3
// 524.116 us; speedup vs baseline: 1.0625x; 1.0625x over previous
//
#include <hip/hip_runtime.h>

#define T_STEPS 1000
#define B_TOT   2048
#define I_IN    40
#define H_N     16
#define TC      25
#define NCHUNK  40
#define EPB     2                  // elems per block = waves per block
#define BLOCK   128
#define XROW    48                 // [t][q][12] quarter layout, 48 floats per t
#define ELEM_LDS (TC*XROW)         // 1200 floats per elem tile
#define LOGITS_OFF 1
#define CORR_OFF  (1 + 2*B_TOT*T_STEPS)   // 4096001
#define TOTAL_OFF (CORR_OFF + 1)          // 4096002

typedef float v2f __attribute__((ext_vector_type(2)));

__global__ void snn_init(float* out) {
    out[0] = 0.0f;
    out[CORR_OFF] = 0.0f;
    out[TOTAL_OFF] = 1216512.0f;   // 594 flagged steps * 2048 batch
}

// quad_perm DPP: pure-VALU cross-lane within quads (fold into v_add_f32_dpp)
__device__ __forceinline__ float dpp_xor1(float v) {
    return __int_as_float(__builtin_amdgcn_update_dpp(0, __float_as_int(v), 0xB1, 0xF, 0xF, true));
}
__device__ __forceinline__ float dpp_xor2(float v) {
    return __int_as_float(__builtin_amdgcn_update_dpp(0, __float_as_int(v), 0x4E, 0xF, 0xF, true));
}

// One wave == one batch element. lane = q(2b) | n(4b). Branch axis lives in the
// v2f pack (v_pk_fma_f32 full-rate), so the branch-sum is an in-lane add and
// the only cross-lane traffic is the 2-stage quad reduction of the dot.
// No __syncthreads anywhere: each wave stages/reads only its own LDS tile.
__global__ __launch_bounds__(BLOCK, 2) void snn_main(
    const float* __restrict__ x, const int* __restrict__ target,
    const float* __restrict__ W1, const float* __restrict__ tau_m,
    const float* __restrict__ tau_n, const float* __restrict__ mask,
    const float* __restrict__ W2, const float* __restrict__ b2,
    float* __restrict__ out)
{
    __shared__ __align__(16) float xbuf[EPB*ELEM_LDS];   // 9.6 KB

    const int tid  = threadIdx.x;
    const int wv   = tid >> 6;            // elem within block
    const int lane = tid & 63;
    const int q    = lane & 3;            // residue class of the 40-dot
    const int n    = lane >> 2;           // neuron 0..15
    const int b    = blockIdx.x * EPB + wv;

    // packed branch weights: wq[j] = (Wm[2n][4j+q], Wm[2n+1][4j+q])
    v2f wq[10];
#pragma unroll
    for (int j = 0; j < 10; ++j) {
        const int i = 4*j + q;
        wq[j] = (v2f){ W1[(2*n)*I_IN + i]   * mask[(2*n)*I_IN + i],
                       W1[(2*n+1)*I_IN + i] * mask[(2*n+1)*I_IN + i] };
    }

    const float alpha = 1.0f / (1.0f + __expf(-tau_m[n]));
    const v2f   beta  = (v2f){ 1.0f / (1.0f + __expf(-tau_n[2*n])),
                               1.0f / (1.0f + __expf(-tau_n[2*n+1])) };
    const float b2v0  = b2[0];
    const float b2v1  = b2[1];
    float w20[H_N], w21[H_N];
#pragma unroll
    for (int nn = 0; nn < H_N; ++nn) { w20[nn] = W2[nn]; w21[nn] = W2[H_N + nn]; }

    // staging: elem tile is contiguous [25t][40i] in x -> unit u = lane+64k,
    // float4 at gbase + 4*u; scatter into quarter layout [t][q][12]
    const long gbase = (long)b * T_STEPS * I_IN;
    const int  u0 = lane, u1 = lane + 64, u2 = lane + 128, u3 = lane + 192;
    const bool v3ok = (u3 < TC*10);       // 250 units per tile
    const int  lbase = wv * ELEM_LDS;
    const int  ls0 = lbase + (u0/10)*XROW + (u0%10);
    const int  ls1 = lbase + (u1/10)*XROW + (u1%10);
    const int  ls2 = lbase + (u2/10)*XROW + (u2%10);
    const int  ls3 = lbase + (u3/10)*XROW + (u3%10);

    float4 pf0 = *(const float4*)(x + gbase + 4*u0);
    float4 pf1 = *(const float4*)(x + gbase + 4*u1);
    float4 pf2 = *(const float4*)(x + gbase + 4*u2);
    float4 pf3 = v3ok ? *(const float4*)(x + gbase + 4*u3) : make_float4(0,0,0,0);

    v2f   d   = (v2f){0.0f, 0.0f};
    float mem = 0.0f, spk = 0.0f;
    float acc_loss = 0.0f, acc_corr = 0.0f;
    unsigned long long cap = 0;

    const float* xq = xbuf + lbase + q*12;

    for (int c = 0; c < NCHUNK; ++c) {
        // scatter stage (wave-private tile; same-wave DS ordering suffices)
        xbuf[ls0] = pf0.x; xbuf[ls0+12] = pf0.y; xbuf[ls0+24] = pf0.z; xbuf[ls0+36] = pf0.w;
        xbuf[ls1] = pf1.x; xbuf[ls1+12] = pf1.y; xbuf[ls1+24] = pf1.z; xbuf[ls1+36] = pf1.w;
        xbuf[ls2] = pf2.x; xbuf[ls2+12] = pf2.y; xbuf[ls2+24] = pf2.z; xbuf[ls2+36] = pf2.w;
        if (v3ok) { xbuf[ls3] = pf3.x; xbuf[ls3+12] = pf3.y; xbuf[ls3+24] = pf3.z; xbuf[ls3+36] = pf3.w; }

        if (c + 1 < NCHUNK) {       // prefetch next tile while computing this one
            const long goff = gbase + (long)(c + 1) * (TC * I_IN);
            pf0 = *(const float4*)(x + goff + 4*u0);
            pf1 = *(const float4*)(x + goff + 4*u1);
            pf2 = *(const float4*)(x + goff + 4*u2);
            if (v3ok) pf3 = *(const float4*)(x + goff + 4*u3);
        }

#pragma unroll
        for (int tt = 0; tt < TC; ++tt) {
            const float* xp = xq + tt*XROW;
            const float4 a0 = *(const float4*)(xp);
            const float4 a1 = *(const float4*)(xp + 4);
            const float2 a2 = *(const float2*)(xp + 8);
            v2f s = (v2f){0.0f, 0.0f};   // (branch0, branch1) partials, j-sequential
            s = __builtin_elementwise_fma(wq[0], (v2f){a0.x, a0.x}, s);
            s = __builtin_elementwise_fma(wq[1], (v2f){a0.y, a0.y}, s);
            s = __builtin_elementwise_fma(wq[2], (v2f){a0.z, a0.z}, s);
            s = __builtin_elementwise_fma(wq[3], (v2f){a0.w, a0.w}, s);
            s = __builtin_elementwise_fma(wq[4], (v2f){a1.x, a1.x}, s);
            s = __builtin_elementwise_fma(wq[5], (v2f){a1.y, a1.y}, s);
            s = __builtin_elementwise_fma(wq[6], (v2f){a1.z, a1.z}, s);
            s = __builtin_elementwise_fma(wq[7], (v2f){a1.w, a1.w}, s);
            s = __builtin_elementwise_fma(wq[8], (v2f){a2.x, a2.x}, s);
            s = __builtin_elementwise_fma(wq[9], (v2f){a2.y, a2.y}, s);
            // quad reduce per branch: (s0+s1)+(s2+s3), same tree as R1 (commutative-exact)
            const float p0 = s.x + dpp_xor1(s.x);
            const float p1 = s.y + dpp_xor1(s.y);
            const v2f cur = (v2f){ p0 + dpp_xor2(p0), p1 + dpp_xor2(p1) };
            d = __builtin_elementwise_fma(beta, d - cur, cur);   // both branches, packed
            const float l = d.x + d.y;                           // branch sum, in-lane
            mem = fmaf(alpha, (mem - spk) - l, l);
            const bool fired = mem > 1.0f;
            spk = fired ? 1.0f : 0.0f;
            const unsigned long long bal = __ballot(fired);
            if (lane == tt) cap = bal;
        }

        // comb: lanes 0..24 handle t = c*25+lane for THIS wave's elem (cap is lane-private)
        if (lane < TC) {
            const int t = c*TC + lane;
            float sL0 = b2v0, sL1 = b2v1;
#pragma unroll
            for (int nn = 0; nn < H_N; ++nn) {   // neuron n fired-bit = ballot bit 4n
                const float f = (float)((unsigned)(cap >> (4*nn)) & 1u);
                sL0 = fmaf(f, w20[nn], sL0);
                sL1 = fmaf(f, w21[nn], sL1);
            }
            const int oidx = (b*T_STEPS + t)*2;
            out[LOGITS_OFF + oidx]     = sL0;
            out[LOGITS_OFF + oidx + 1] = sL1;
            const bool flag = (t > 10) && (((t - 10) % 15) > 5);
            if (flag) {
                const int tgt = target[b*T_STEPS + t];
                float mx  = fmaxf(sL0, sL1);
                float e0  = __expf(sL0 - mx), e1 = __expf(sL1 - mx);
                float inv = 1.0f / (e0 + e1);
                float p0s = e0*inv, p1s = e1*inv;
                float mm  = fmaxf(p0s, p1s);
                float lse = mm + __logf(__expf(p0s - mm) + __expf(p1s - mm));
                float qv  = ((tgt == 1) ? p1s : p0s) - lse;
                acc_loss -= qv;
                const int pred = (p1s > p0s) ? 1 : 0;
                acc_corr += (pred == tgt) ? 1.0f : 0.0f;
            }
        }
    }

    acc_loss *= (1.0f / (float)B_TOT);
#pragma unroll
    for (int mk = 1; mk < 64; mk <<= 1) {
        acc_loss += __shfl_xor(acc_loss, mk, 64);
        acc_corr += __shfl_xor(acc_corr, mk, 64);
    }
    if (lane == 0) {
        atomicAdd(out, acc_loss);
        atomicAdd(out + CORR_OFF, acc_corr);
    }
}

extern "C" void kernel_launch(void* const* d_in, const int* in_sizes, int n_in,
                              void* d_out, int out_size, void* d_ws, size_t ws_size,
                              hipStream_t stream) {
    const float* x      = (const float*)d_in[0];
    const int*   target = (const int*)d_in[1];
    const float* W1     = (const float*)d_in[2];
    const float* tau_m  = (const float*)d_in[3];
    const float* tau_n  = (const float*)d_in[4];
    const float* mask   = (const float*)d_in[5];
    const float* W2     = (const float*)d_in[6];
    const float* b2     = (const float*)d_in[7];
    float* out = (float*)d_out;

    snn_init<<<1, 1, 0, stream>>>(out);
    snn_main<<<B_TOT/EPB, BLOCK, 0, stream>>>(x, target, W1, tau_m, tau_n, mask, W2, b2, out);
}